// Round 19
// baseline (31.529 us; speedup 1.0000x reference)
//
#include <hip/hip_runtime.h>
#include <hip/hip_bf16.h>
#include <math.h>

#define B_ 128
#define IN_ 1024
#define D_ 128
#define H_ 512
#define S_ 256

typedef __attribute__((ext_vector_type(8))) short short8v;
typedef __attribute__((ext_vector_type(8))) unsigned short ushort8v;
typedef __attribute__((ext_vector_type(4))) unsigned short ushort4v;
typedef __attribute__((ext_vector_type(4))) float f32x4;

__device__ __forceinline__ float softplusf(float x) {
  return fmaxf(x, 0.f) + log1pf(expf(-fabsf(x)));
}

__device__ __forceinline__ unsigned short f2bf(float f) {
  unsigned u = __float_as_uint(f);
  unsigned r = (u + 0x7fff + ((u >> 16) & 1)) >> 16;   // RNE
  return (unsigned short)r;
}

// load 8 consecutive fp32 at p, convert to bf16 fragment
__device__ __forceinline__ short8v ld_frag8(const float* __restrict__ p) {
  const float4 v0 = *(const float4*)(p);
  const float4 v1 = *(const float4*)(p + 4);
  short8v s;
  s[0] = (short)f2bf(v0.x); s[1] = (short)f2bf(v0.y);
  s[2] = (short)f2bf(v0.z); s[3] = (short)f2bf(v0.w);
  s[4] = (short)f2bf(v1.x); s[5] = (short)f2bf(v1.y);
  s[6] = (short)f2bf(v1.z); s[7] = (short)f2bf(v1.w);
  return s;
}

union SMemP {
  struct { float xs[16][128]; float redp[4][16]; } px;
  struct { float redp[4][16]; } zw;
  struct { float xs[64]; float p2[256]; } pw;
};

// ============ Kprep3 (R18 byte-identical): 2208 blocks x 256 ============
__global__ __launch_bounds__(256) void Kprep3(
    const float* __restrict__ x, const float* __restrict__ w,
    const float* __restrict__ z, const float* __restrict__ W,
    const float* __restrict__ cvec, const float* __restrict__ W1,
    const float* __restrict__ b1, const float* __restrict__ W2,
    unsigned short* __restrict__ Bp, float* __restrict__ l2part,
    float* __restrict__ zb1, float* __restrict__ pxw_part,
    float* __restrict__ fzw_part) {
  __shared__ SMemP sm;
  const int blk = blockIdx.x;
  const int t = threadIdx.x;
  const int lane = t & 63, wv = t >> 6;

  if (blk < 64) {
    const int o = (blk * 256 + t) * 4;
    const int frag = o >> 9;
    const int l = (o >> 3) & 63;
    const int j0 = o & 7;
    const int h = (frag >> 2) * 16 + (l & 15);
    const int k0 = (frag & 3) * 32 + ((l >> 4) << 3) + j0;
    const float4 v = *(const float4*)(W1 + (size_t)h * 256 + 128 + k0);
    ushort4v u;
    u[0] = f2bf(v.x); u[1] = f2bf(v.y); u[2] = f2bf(v.z); u[3] = f2bf(v.w);
    *(ushort4v*)(Bp + o) = u;
  } else if (blk < 128) {
    const int bb = blk - 64;
    const int bt = bb >> 3, ic = bb & 7;
    {
      const int row = t >> 4, c8 = (t & 15) * 8;
      const float* __restrict__ src = x + (size_t)(bt * 16 + row) * IN_ + ic * 128 + c8;
      *(float4*)&sm.px.xs[row][c8]     = *(const float4*)(src);
      *(float4*)&sm.px.xs[row][c8 + 4] = *(const float4*)(src + 4);
    }
    short8v a[4];
    const int arow = bt * 16 + (lane & 15);
    const int k0 = (lane >> 4) * 8;
    #pragma unroll
    for (int ks = 0; ks < 4; ++ks)
      a[ks] = ld_frag8(w + (size_t)arow * D_ + ks * 32 + k0);
    __syncthreads();

    float term[4] = {0.f, 0.f, 0.f, 0.f};
    #pragma unroll
    for (int itl = 0; itl < 2; ++itl) {
      const int itile = wv * 2 + itl;
      const int git = ic * 8 + itile;
      const int irow = git * 16 + (lane & 15);
      f32x4 acc = {0.f, 0.f, 0.f, 0.f};
      #pragma unroll
      for (int ks = 0; ks < 4; ++ks) {
        const short8v bfr = ld_frag8(W + (size_t)irow * D_ + ks * 32 + k0);
        acc = __builtin_amdgcn_mfma_f32_16x16x32_bf16(a[ks], bfr, acc, 0, 0, 0);
      }
      const int iloc = itile * 16 + (lane & 15);
      const float cv = cvec[ic * 128 + iloc];
      #pragma unroll
      for (int j = 0; j < 4; ++j) {
        const int rloc = (lane >> 4) * 4 + j;
        const float lg = acc[j] + cv;
        term[j] += sm.px.xs[rloc][iloc] * lg - softplusf(lg);
      }
    }
    #pragma unroll
    for (int j = 0; j < 4; ++j) {
      float v = term[j];
      v += __shfl_xor(v, 1); v += __shfl_xor(v, 2);
      v += __shfl_xor(v, 4); v += __shfl_xor(v, 8);
      if ((lane & 15) == 0) sm.px.redp[wv][(lane >> 4) * 4 + j] = v;
    }
    __syncthreads();
    if (t < 16)
      pxw_part[(size_t)(bt * 16 + t) * 8 + ic] =
          sm.px.redp[0][t] + sm.px.redp[1][t] + sm.px.redp[2][t] + sm.px.redp[3][t];
  } else if (blk < 160) {
    const int bb = blk - 128;
    const int bt = bb >> 2, hc = bb & 3;
    short8v az[4], aw[4];
    const int arow = bt * 16 + (lane & 15);
    const int k0 = (lane >> 4) * 8;
    #pragma unroll
    for (int ks = 0; ks < 4; ++ks) {
      az[ks] = ld_frag8(z + (size_t)arow * D_ + ks * 32 + k0);
      aw[ks] = ld_frag8(w + (size_t)arow * D_ + ks * 32 + k0);
    }
    float term[4] = {0.f, 0.f, 0.f, 0.f};
    #pragma unroll
    for (int htl = 0; htl < 2; ++htl) {
      const int ghb = hc * 8 + wv * 2 + htl;
      const int h = ghb * 16 + (lane & 15);
      f32x4 accz = {0.f, 0.f, 0.f, 0.f};
      f32x4 accw = {0.f, 0.f, 0.f, 0.f};
      #pragma unroll
      for (int ks = 0; ks < 4; ++ks) {
        const short8v bz = ld_frag8(W1 + (size_t)h * 256 + ks * 32 + k0);
        const short8v bw = ld_frag8(W1 + (size_t)h * 256 + 128 + ks * 32 + k0);
        accz = __builtin_amdgcn_mfma_f32_16x16x32_bf16(az[ks], bz, accz, 0, 0, 0);
        accw = __builtin_amdgcn_mfma_f32_16x16x32_bf16(aw[ks], bw, accw, 0, 0, 0);
      }
      const float b1v = b1[h], w2v = W2[h];
      #pragma unroll
      for (int j = 0; j < 4; ++j) {
        const int brow = bt * 16 + (lane >> 4) * 4 + j;
        const float zp = accz[j] + b1v;
        zb1[(size_t)brow * H_ + h] = zp;
        term[j] += fmaxf(zp + accw[j], 0.f) * w2v;
      }
    }
    #pragma unroll
    for (int j = 0; j < 4; ++j) {
      float v = term[j];
      v += __shfl_xor(v, 1); v += __shfl_xor(v, 2);
      v += __shfl_xor(v, 4); v += __shfl_xor(v, 8);
      if ((lane & 15) == 0) sm.zw.redp[wv][(lane >> 4) * 4 + j] = v;
    }
    __syncthreads();
    if (t < 16)
      fzw_part[(size_t)(bt * 16 + t) * 4 + hc] =
          sm.zw.redp[0][t] + sm.zw.redp[1][t] + sm.zw.redp[2][t] + sm.zw.redp[3][t];
  } else {
    const int bb = blk - 160;
    const int b = bb >> 4, kc = bb & 15;
    float* xs = sm.pw.xs;
    float* p2 = sm.pw.p2;
    if (t < 64) xs[t] = x[b * IN_ + kc * 64 + t];
    __syncthreads();
    const int d = t & 127, ks = t >> 7;
    const float* __restrict__ Wp = W + (size_t)(kc * 64 + ks * 32) * D_ + d;
    float s = 0.f;
    #pragma unroll 8
    for (int i = 0; i < 32; ++i) s = fmaf(xs[ks * 32 + i], Wp[(size_t)i * D_], s);
    p2[ks * 128 + d] = s;
    __syncthreads();
    if (t < 128) l2part[((size_t)b * 16 + kc) * 128 + t] = p2[t] + p2[128 + t];
  }
}

// ============ MFMA GEMM: 512 blocks x 256 thr, block = (sq of 8, b-pair) ============
// Each block: 2 b's x 32 s-rows; Bp fragment loaded once, fed to 4 MFMA (2b x 2m).
__global__ __launch_bounds__(256) void Kmfma(
    const float* __restrict__ wt, const unsigned short* __restrict__ Bp,
    const float* __restrict__ zb1, const float* __restrict__ W2,
    const float* __restrict__ b2, float* __restrict__ mpart,
    float* __restrict__ lpart) {
  const int blk = blockIdx.x;            // 512 = sq*64 + bp
  const int bp = blk & 63;
  const int b0 = bp * 2;
  const int sq = blk >> 6;               // 0..7
  const int s0 = sq * 32;
  const int t = threadIdx.x;
  const int lane = t & 63, wv = t >> 6;  // 4 waves

  __shared__ unsigned short atile[2][32 * 128];  // 16 KB, XOR-swizzled bf16
  __shared__ float zb1s[2][H_];
  __shared__ float w2s[H_];
  __shared__ float red[4][2][32];

  zb1s[0][t] = zb1[(size_t)b0 * H_ + t];
  zb1s[0][256 + t] = zb1[(size_t)b0 * H_ + 256 + t];
  zb1s[1][t] = zb1[(size_t)(b0 + 1) * H_ + t];
  zb1s[1][256 + t] = zb1[(size_t)(b0 + 1) * H_ + 256 + t];
  w2s[t] = W2[t];
  w2s[256 + t] = W2[256 + t];

  // stage A: 2 tiles of 32 rows x 128 d, fp32 -> bf16, swizzle g ^= r&15
  {
    const int bsel = t >> 7;             // 0/1
    const int tt = t & 127;
    const int r = tt >> 2;               // 0..31
    const int g0 = (tt & 3) * 4;
    const float* __restrict__ src = wt + ((size_t)(s0 + r) * B_ + b0 + bsel) * D_;
    #pragma unroll
    for (int gg = 0; gg < 4; ++gg) {
      const int g = g0 + gg;
      const float4 v0 = *(const float4*)(src + g * 8);
      const float4 v1 = *(const float4*)(src + g * 8 + 4);
      ushort8v u;
      u[0] = f2bf(v0.x); u[1] = f2bf(v0.y); u[2] = f2bf(v0.z); u[3] = f2bf(v0.w);
      u[4] = f2bf(v1.x); u[5] = f2bf(v1.y); u[6] = f2bf(v1.z); u[7] = f2bf(v1.w);
      *(ushort8v*)&atile[bsel][r * 128 + ((g ^ (r & 15)) << 3)] = u;
    }
  }
  __syncthreads();

  // A fragments: row = m*16 + (lane&15), k = ks*32 + (lane>>4)*8 + j
  short8v afr[2][2][4];
  #pragma unroll
  for (int bb = 0; bb < 2; ++bb)
    #pragma unroll
    for (int m = 0; m < 2; ++m) {
      const int arow = m * 16 + (lane & 15);
      #pragma unroll
      for (int ks = 0; ks < 4; ++ks) {
        const int g = ks * 4 + (lane >> 4);
        afr[bb][m][ks] = *(const short8v*)&atile[bb][arow * 128 + ((g ^ (arow & 15)) << 3)];
      }
    }

  float fsum[2][2][4];
  #pragma unroll
  for (int bb = 0; bb < 2; ++bb)
    #pragma unroll
    for (int m = 0; m < 2; ++m)
      #pragma unroll
      for (int j = 0; j < 4; ++j) fsum[bb][m][j] = 0.f;

  const int hl = lane & 15;
  #pragma unroll 2
  for (int nt = 0; nt < 8; ++nt) {
    const int hblk = wv * 8 + nt;        // 0..31
    const int hrow = hblk * 16 + hl;
    f32x4 acc00 = {0.f,0.f,0.f,0.f}, acc01 = {0.f,0.f,0.f,0.f};
    f32x4 acc10 = {0.f,0.f,0.f,0.f}, acc11 = {0.f,0.f,0.f,0.f};
    #pragma unroll
    for (int ks = 0; ks < 4; ++ks) {
      const int frag = hblk * 4 + ks;
      const short8v bfr = *(const short8v*)(Bp + ((size_t)frag << 9) + (lane << 3));
      acc00 = __builtin_amdgcn_mfma_f32_16x16x32_bf16(afr[0][0][ks], bfr, acc00, 0, 0, 0);
      acc01 = __builtin_amdgcn_mfma_f32_16x16x32_bf16(afr[0][1][ks], bfr, acc01, 0, 0, 0);
      acc10 = __builtin_amdgcn_mfma_f32_16x16x32_bf16(afr[1][0][ks], bfr, acc10, 0, 0, 0);
      acc11 = __builtin_amdgcn_mfma_f32_16x16x32_bf16(afr[1][1][ks], bfr, acc11, 0, 0, 0);
    }
    const float zv0 = zb1s[0][hrow], zv1 = zb1s[1][hrow], wgt = w2s[hrow];
    #pragma unroll
    for (int j = 0; j < 4; ++j) {
      fsum[0][0][j] += fmaxf(acc00[j] + zv0, 0.f) * wgt;
      fsum[0][1][j] += fmaxf(acc01[j] + zv0, 0.f) * wgt;
      fsum[1][0][j] += fmaxf(acc10[j] + zv1, 0.f) * wgt;
      fsum[1][1][j] += fmaxf(acc11[j] + zv1, 0.f) * wgt;
    }
  }
  // reduce over 16 h-columns (lane bits 0..3)
  #pragma unroll
  for (int bb = 0; bb < 2; ++bb)
    #pragma unroll
    for (int m = 0; m < 2; ++m)
      #pragma unroll
      for (int j = 0; j < 4; ++j) {
        float v = fsum[bb][m][j];
        v += __shfl_xor(v, 1); v += __shfl_xor(v, 2);
        v += __shfl_xor(v, 4); v += __shfl_xor(v, 8);
        fsum[bb][m][j] = v;
      }
  if (hl == 0) {
    const int rb = (lane >> 4) * 4;
    #pragma unroll
    for (int bb = 0; bb < 2; ++bb)
      #pragma unroll
      for (int m = 0; m < 2; ++m)
        #pragma unroll
        for (int j = 0; j < 4; ++j)
          red[wv][bb][m * 16 + rb + j] = fsum[bb][m][j];
  }
  __syncthreads();

  // partial logsumexp: lanes 0..31 -> b0's 32 rows, lanes 32..63 -> b1's
  if (t < 64) {
    const int bb = t >> 5, r = t & 31;
    const float fval = red[0][bb][r] + red[1][bb][r] + red[2][bb][r] + red[3][bb][r] + b2[0];
    float mm = fval;
    #pragma unroll
    for (int o = 1; o < 32; o <<= 1) mm = fmaxf(mm, __shfl_xor(mm, o));
    float e = expf(fval - mm);
    #pragma unroll
    for (int o = 1; o < 32; o <<= 1) e += __shfl_xor(e, o);
    if (r == 0) { mpart[sq * 128 + b0 + bb] = mm; lpart[sq * 128 + b0 + bb] = e; }
  }
}

// ============ finisher (R18 byte-identical): 128 blocks x 128 thr ============
__global__ __launch_bounds__(128) void Kfin(
    const float* __restrict__ mpart, const float* __restrict__ lpart,
    const float* __restrict__ l2part, const float* __restrict__ bvec,
    const float* __restrict__ w, const float* __restrict__ pxw_part,
    const float* __restrict__ fzw_part, const float* __restrict__ b2,
    float* __restrict__ out) {
  const int b = blockIdx.x, t = threadIdx.x;
  __shared__ float red3[2];
  const int lane = t & 63, wid = t >> 6;
  float lg = bvec[t];
  #pragma unroll
  for (int kc = 0; kc < 16; ++kc) lg += l2part[((size_t)b * 16 + kc) * 128 + t];
  float term = w[b * 128 + t] * lg - softplusf(lg);
  #pragma unroll
  for (int o = 1; o < 64; o <<= 1) term += __shfl_xor(term, o);
  if (lane == 0) red3[wid] = term;
  __syncthreads();
  if (t == 0) {
    const float pwx = red3[0] + red3[1];
    float mm = mpart[b];
    #pragma unroll
    for (int q = 1; q < 8; ++q) mm = fmaxf(mm, mpart[q * 128 + b]);
    float l = 0.f;
    #pragma unroll
    for (int q = 0; q < 8; ++q) l += lpart[q * 128 + b] * expf(mpart[q * 128 + b] - mm);
    const float logZ = mm + logf(l) - logf((float)S_) + (float)D_ * logf(2.f);
    float pxw = 0.f;
    #pragma unroll
    for (int ic = 0; ic < 8; ++ic) pxw += pxw_part[(size_t)b * 8 + ic];
    float fzw = b2[0];
    #pragma unroll
    for (int hc = 0; hc < 4; ++hc) fzw += fzw_part[(size_t)b * 4 + hc];
    const float r_wz = fminf(fzw - logZ, 0.f);
    out[b] = -(pxw - pwx + r_wz);
  }
}

extern "C" void kernel_launch(void* const* d_in, const int* in_sizes, int n_in,
                              void* d_out, int out_size, void* d_ws, size_t ws_size,
                              hipStream_t stream) {
  const float* x    = (const float*)d_in[0];
  // d_in[1] = y, unused
  const float* w    = (const float*)d_in[2];
  const float* z    = (const float*)d_in[3];
  const float* wt   = (const float*)d_in[4];
  const float* W    = (const float*)d_in[5];
  const float* bvec = (const float*)d_in[6];
  const float* cvec = (const float*)d_in[7];
  const float* W1   = (const float*)d_in[8];
  const float* b1   = (const float*)d_in[9];
  const float* W2   = (const float*)d_in[10];
  const float* b2   = (const float*)d_in[11];

  float* ws_f = (float*)d_ws;
  unsigned short* Bp    = (unsigned short*)ws_f;              // 65536 us = 32768 f
  float* zb1            = ws_f + 32768;                       // 65536 f
  float* l2part         = ws_f + 98304;                       // 262144 f
  float* pxw_part       = ws_f + 360448;                      // 1024 f
  float* fzw_part       = ws_f + 361472;                      // 512 f
  float* mpart          = ws_f + 361984;                      // 1024 f
  float* lpart          = ws_f + 363008;                      // 1024 f
  float* out = (float*)d_out;

  hipLaunchKernelGGL(Kprep3, dim3(2208), dim3(256), 0, stream,
                     x, w, z, W, cvec, W1, b1, W2, Bp, l2part, zb1, pxw_part, fzw_part);
  hipLaunchKernelGGL(Kmfma, dim3(512), dim3(256), 0, stream,
                     wt, Bp, zb1, W2, b2, mpart, lpart);
  hipLaunchKernelGGL(Kfin, dim3(B_), dim3(128), 0, stream,
                     mpart, lpart, l2part, bvec, w, pxw_part, fzw_part, b2, out);
}

// Round 20
// 26.398 us; speedup vs baseline: 1.1944x; 1.1944x over previous
//
#include <hip/hip_runtime.h>
#include <hip/hip_bf16.h>
#include <math.h>

#define B_ 128
#define IN_ 1024
#define D_ 128
#define H_ 512
#define S_ 256

typedef __attribute__((ext_vector_type(8))) short short8v;
typedef __attribute__((ext_vector_type(8))) unsigned short ushort8v;
typedef __attribute__((ext_vector_type(4))) unsigned short ushort4v;
typedef __attribute__((ext_vector_type(4))) float f32x4;

__device__ __forceinline__ float softplusf(float x) {
  return fmaxf(x, 0.f) + log1pf(expf(-fabsf(x)));
}

__device__ __forceinline__ unsigned short f2bf(float f) {
  unsigned u = __float_as_uint(f);
  unsigned r = (u + 0x7fff + ((u >> 16) & 1)) >> 16;   // RNE
  return (unsigned short)r;
}

// load 8 consecutive fp32 at p, convert to bf16 fragment
__device__ __forceinline__ short8v ld_frag8(const float* __restrict__ p) {
  const float4 v0 = *(const float4*)(p);
  const float4 v1 = *(const float4*)(p + 4);
  short8v s;
  s[0] = (short)f2bf(v0.x); s[1] = (short)f2bf(v0.y);
  s[2] = (short)f2bf(v0.z); s[3] = (short)f2bf(v0.w);
  s[4] = (short)f2bf(v1.x); s[5] = (short)f2bf(v1.y);
  s[6] = (short)f2bf(v1.z); s[7] = (short)f2bf(v1.w);
  return s;
}

union SMemP {
  struct { float xs[16][128]; float redp[4][16]; } px;
  struct { float redp[4][16]; } zw;
  struct { float xs[64]; float p2[256]; } pw;
};

// ============ Kprep3 (R18 best-measured): 2208 blocks x 256 ============
// [0,64)      : Bp pack (verified)
// [64,128)    : pxw MFMA, inline W fragments (verified)
// [128,160)   : zw MFMA, inline W1 fragments (verified)
// [160,2208)  : pwx partial logits (64 i-rows, kc of 16)
__global__ __launch_bounds__(256) void Kprep3(
    const float* __restrict__ x, const float* __restrict__ w,
    const float* __restrict__ z, const float* __restrict__ W,
    const float* __restrict__ cvec, const float* __restrict__ W1,
    const float* __restrict__ b1, const float* __restrict__ W2,
    unsigned short* __restrict__ Bp, float* __restrict__ l2part,
    float* __restrict__ zb1, float* __restrict__ pxw_part,
    float* __restrict__ fzw_part) {
  __shared__ SMemP sm;
  const int blk = blockIdx.x;
  const int t = threadIdx.x;
  const int lane = t & 63, wv = t >> 6;

  if (blk < 64) {
    // ---- Bp pack (verified)
    const int o = (blk * 256 + t) * 4;
    const int frag = o >> 9;
    const int l = (o >> 3) & 63;
    const int j0 = o & 7;
    const int h = (frag >> 2) * 16 + (l & 15);
    const int k0 = (frag & 3) * 32 + ((l >> 4) << 3) + j0;
    const float4 v = *(const float4*)(W1 + (size_t)h * 256 + 128 + k0);
    ushort4v u;
    u[0] = f2bf(v.x); u[1] = f2bf(v.y); u[2] = f2bf(v.z); u[3] = f2bf(v.w);
    *(ushort4v*)(Bp + o) = u;
  } else if (blk < 128) {
    // ================= pxw MFMA (verified) =================
    const int bb = blk - 64;
    const int bt = bb >> 3, ic = bb & 7;
    {
      const int row = t >> 4, c8 = (t & 15) * 8;
      const float* __restrict__ src = x + (size_t)(bt * 16 + row) * IN_ + ic * 128 + c8;
      *(float4*)&sm.px.xs[row][c8]     = *(const float4*)(src);
      *(float4*)&sm.px.xs[row][c8 + 4] = *(const float4*)(src + 4);
    }
    short8v a[4];
    const int arow = bt * 16 + (lane & 15);
    const int k0 = (lane >> 4) * 8;
    #pragma unroll
    for (int ks = 0; ks < 4; ++ks)
      a[ks] = ld_frag8(w + (size_t)arow * D_ + ks * 32 + k0);
    __syncthreads();

    float term[4] = {0.f, 0.f, 0.f, 0.f};
    #pragma unroll
    for (int itl = 0; itl < 2; ++itl) {
      const int itile = wv * 2 + itl;
      const int git = ic * 8 + itile;
      const int irow = git * 16 + (lane & 15);
      f32x4 acc = {0.f, 0.f, 0.f, 0.f};
      #pragma unroll
      for (int ks = 0; ks < 4; ++ks) {
        const short8v bfr = ld_frag8(W + (size_t)irow * D_ + ks * 32 + k0);
        acc = __builtin_amdgcn_mfma_f32_16x16x32_bf16(a[ks], bfr, acc, 0, 0, 0);
      }
      const int iloc = itile * 16 + (lane & 15);
      const float cv = cvec[ic * 128 + iloc];
      #pragma unroll
      for (int j = 0; j < 4; ++j) {
        const int rloc = (lane >> 4) * 4 + j;
        const float lg = acc[j] + cv;
        term[j] += sm.px.xs[rloc][iloc] * lg - softplusf(lg);
      }
    }
    #pragma unroll
    for (int j = 0; j < 4; ++j) {
      float v = term[j];
      v += __shfl_xor(v, 1); v += __shfl_xor(v, 2);
      v += __shfl_xor(v, 4); v += __shfl_xor(v, 8);
      if ((lane & 15) == 0) sm.px.redp[wv][(lane >> 4) * 4 + j] = v;
    }
    __syncthreads();
    if (t < 16)
      pxw_part[(size_t)(bt * 16 + t) * 8 + ic] =
          sm.px.redp[0][t] + sm.px.redp[1][t] + sm.px.redp[2][t] + sm.px.redp[3][t];
  } else if (blk < 160) {
    // ================= zw MFMA (verified) =================
    const int bb = blk - 128;
    const int bt = bb >> 2, hc = bb & 3;
    short8v az[4], aw[4];
    const int arow = bt * 16 + (lane & 15);
    const int k0 = (lane >> 4) * 8;
    #pragma unroll
    for (int ks = 0; ks < 4; ++ks) {
      az[ks] = ld_frag8(z + (size_t)arow * D_ + ks * 32 + k0);
      aw[ks] = ld_frag8(w + (size_t)arow * D_ + ks * 32 + k0);
    }
    float term[4] = {0.f, 0.f, 0.f, 0.f};
    #pragma unroll
    for (int htl = 0; htl < 2; ++htl) {
      const int ghb = hc * 8 + wv * 2 + htl;
      const int h = ghb * 16 + (lane & 15);
      f32x4 accz = {0.f, 0.f, 0.f, 0.f};
      f32x4 accw = {0.f, 0.f, 0.f, 0.f};
      #pragma unroll
      for (int ks = 0; ks < 4; ++ks) {
        const short8v bz = ld_frag8(W1 + (size_t)h * 256 + ks * 32 + k0);
        const short8v bw = ld_frag8(W1 + (size_t)h * 256 + 128 + ks * 32 + k0);
        accz = __builtin_amdgcn_mfma_f32_16x16x32_bf16(az[ks], bz, accz, 0, 0, 0);
        accw = __builtin_amdgcn_mfma_f32_16x16x32_bf16(aw[ks], bw, accw, 0, 0, 0);
      }
      const float b1v = b1[h], w2v = W2[h];
      #pragma unroll
      for (int j = 0; j < 4; ++j) {
        const int brow = bt * 16 + (lane >> 4) * 4 + j;
        const float zp = accz[j] + b1v;
        zb1[(size_t)brow * H_ + h] = zp;
        term[j] += fmaxf(zp + accw[j], 0.f) * w2v;
      }
    }
    #pragma unroll
    for (int j = 0; j < 4; ++j) {
      float v = term[j];
      v += __shfl_xor(v, 1); v += __shfl_xor(v, 2);
      v += __shfl_xor(v, 4); v += __shfl_xor(v, 8);
      if ((lane & 15) == 0) sm.zw.redp[wv][(lane >> 4) * 4 + j] = v;
    }
    __syncthreads();
    if (t < 16)
      fzw_part[(size_t)(bt * 16 + t) * 4 + hc] =
          sm.zw.redp[0][t] + sm.zw.redp[1][t] + sm.zw.redp[2][t] + sm.zw.redp[3][t];
  } else {
    // ================= pwx partial (64 i-rows per block) =================
    const int bb = blk - 160;
    const int b = bb >> 4, kc = bb & 15;
    float* xs = sm.pw.xs;
    float* p2 = sm.pw.p2;
    if (t < 64) xs[t] = x[b * IN_ + kc * 64 + t];
    __syncthreads();
    const int d = t & 127, ks = t >> 7;
    const float* __restrict__ Wp = W + (size_t)(kc * 64 + ks * 32) * D_ + d;
    float s = 0.f;
    #pragma unroll 8
    for (int i = 0; i < 32; ++i) s = fmaf(xs[ks * 32 + i], Wp[(size_t)i * D_], s);
    p2[ks * 128 + d] = s;
    __syncthreads();
    if (t < 128) l2part[((size_t)b * 16 + kc) * 128 + t] = p2[t] + p2[128 + t];
  }
}

// ============ MFMA GEMM (R18 best-measured): 1024 blocks x 256 thr ============
__global__ __launch_bounds__(256) void Kmfma(
    const float* __restrict__ wt, const unsigned short* __restrict__ Bp,
    const float* __restrict__ zb1, const float* __restrict__ W2,
    const float* __restrict__ b2, float* __restrict__ mpart,
    float* __restrict__ lpart) {
  const int blk = blockIdx.x;            // 1024 = sq*128 + b
  const int b = blk & (B_ - 1);
  const int sq = blk >> 7;               // 0..7
  const int s0 = sq * 32;
  const int t = threadIdx.x;
  const int lane = t & 63, wv = t >> 6;  // 4 waves

  __shared__ unsigned short atile[32 * 128];   // 8 KB, XOR-swizzled bf16
  __shared__ float zb1s[H_];
  __shared__ float w2s[H_];
  __shared__ float red[4][32];

  zb1s[t] = zb1[(size_t)b * H_ + t];
  zb1s[256 + t] = zb1[(size_t)b * H_ + 256 + t];
  w2s[t] = W2[t];
  w2s[256 + t] = W2[256 + t];

  // stage A: 32 rows x 128 d, fp32 -> bf16, granule swizzle g ^= r&15 (verified)
  {
    const int r = t >> 3;                // 0..31
    const int g0 = (t & 7) * 2;
    const float* __restrict__ src = wt + ((size_t)(s0 + r) * B_ + b) * D_;
    #pragma unroll
    for (int gg = 0; gg < 2; ++gg) {
      const int g = g0 + gg;
      const float4 v0 = *(const float4*)(src + g * 8);
      const float4 v1 = *(const float4*)(src + g * 8 + 4);
      ushort8v u;
      u[0] = f2bf(v0.x); u[1] = f2bf(v0.y); u[2] = f2bf(v0.z); u[3] = f2bf(v0.w);
      u[4] = f2bf(v1.x); u[5] = f2bf(v1.y); u[6] = f2bf(v1.z); u[7] = f2bf(v1.w);
      *(ushort8v*)&atile[r * 128 + ((g ^ (r & 15)) << 3)] = u;
    }
  }
  __syncthreads();

  // A fragments (verified mapping): row = m*16 + (lane&15)
  short8v afr[2][4];
  #pragma unroll
  for (int m = 0; m < 2; ++m) {
    const int arow = m * 16 + (lane & 15);
    #pragma unroll
    for (int ks = 0; ks < 4; ++ks) {
      const int g = ks * 4 + (lane >> 4);
      afr[m][ks] = *(const short8v*)&atile[arow * 128 + ((g ^ (arow & 15)) << 3)];
    }
  }

  float fsum[2][4];
  #pragma unroll
  for (int m = 0; m < 2; ++m)
    #pragma unroll
    for (int j = 0; j < 4; ++j) fsum[m][j] = 0.f;

  const int hl = lane & 15;
  #pragma unroll 2
  for (int nt = 0; nt < 8; ++nt) {
    const int hblk = wv * 8 + nt;        // 0..31
    const int hrow = hblk * 16 + hl;
    f32x4 acc0 = {0.f,0.f,0.f,0.f}, acc1 = {0.f,0.f,0.f,0.f};
    #pragma unroll
    for (int ks = 0; ks < 4; ++ks) {
      const int frag = hblk * 4 + ks;
      const short8v bfr = *(const short8v*)(Bp + ((size_t)frag << 9) + (lane << 3));
      acc0 = __builtin_amdgcn_mfma_f32_16x16x32_bf16(afr[0][ks], bfr, acc0, 0, 0, 0);
      acc1 = __builtin_amdgcn_mfma_f32_16x16x32_bf16(afr[1][ks], bfr, acc1, 0, 0, 0);
    }
    const float zv = zb1s[hrow], wgt = w2s[hrow];
    #pragma unroll
    for (int j = 0; j < 4; ++j) {
      fsum[0][j] += fmaxf(acc0[j] + zv, 0.f) * wgt;
      fsum[1][j] += fmaxf(acc1[j] + zv, 0.f) * wgt;
    }
  }
  // reduce over 16 h-columns (lane bits 0..3)
  #pragma unroll
  for (int m = 0; m < 2; ++m)
    #pragma unroll
    for (int j = 0; j < 4; ++j) {
      float v = fsum[m][j];
      v += __shfl_xor(v, 1); v += __shfl_xor(v, 2);
      v += __shfl_xor(v, 4); v += __shfl_xor(v, 8);
      fsum[m][j] = v;
    }
  if (hl == 0) {
    const int rb = (lane >> 4) * 4;
    #pragma unroll
    for (int m = 0; m < 2; ++m)
      #pragma unroll
      for (int j = 0; j < 4; ++j)
        red[wv][m * 16 + rb + j] = fsum[m][j];
  }
  __syncthreads();

  // partial logsumexp over this block's 32 f values (lanes 0..31 of wave 0)
  if (t < 32) {
    const float fval = red[0][t] + red[1][t] + red[2][t] + red[3][t] + b2[0];
    float mm = fval;
    #pragma unroll
    for (int o = 1; o < 32; o <<= 1) mm = fmaxf(mm, __shfl_xor(mm, o));
    float e = expf(fval - mm);
    #pragma unroll
    for (int o = 1; o < 32; o <<= 1) e += __shfl_xor(e, o);
    if (t == 0) { mpart[blk] = mm; lpart[blk] = e; }
  }
}

// ============ finisher (R18 best-measured): 128 blocks x 128 thr ============
__global__ __launch_bounds__(128) void Kfin(
    const float* __restrict__ mpart, const float* __restrict__ lpart,
    const float* __restrict__ l2part, const float* __restrict__ bvec,
    const float* __restrict__ w, const float* __restrict__ pxw_part,
    const float* __restrict__ fzw_part, const float* __restrict__ b2,
    float* __restrict__ out) {
  const int b = blockIdx.x, t = threadIdx.x;
  __shared__ float red3[2];
  const int lane = t & 63, wid = t >> 6;
  // pwx finish
  float lg = bvec[t];
  #pragma unroll
  for (int kc = 0; kc < 16; ++kc) lg += l2part[((size_t)b * 16 + kc) * 128 + t];
  float term = w[b * 128 + t] * lg - softplusf(lg);
  #pragma unroll
  for (int o = 1; o < 64; o <<= 1) term += __shfl_xor(term, o);
  if (lane == 0) red3[wid] = term;
  __syncthreads();
  if (t == 0) {
    const float pwx = red3[0] + red3[1];
    // combine 8 logsumexp partials
    float mm = mpart[b];
    #pragma unroll
    for (int q = 1; q < 8; ++q) mm = fmaxf(mm, mpart[q * 128 + b]);
    float l = 0.f;
    #pragma unroll
    for (int q = 0; q < 8; ++q) l += lpart[q * 128 + b] * expf(mpart[q * 128 + b] - mm);
    const float logZ = mm + logf(l) - logf((float)S_) + (float)D_ * logf(2.f);
    float pxw = 0.f;
    #pragma unroll
    for (int ic = 0; ic < 8; ++ic) pxw += pxw_part[(size_t)b * 8 + ic];
    float fzw = b2[0];
    #pragma unroll
    for (int hc = 0; hc < 4; ++hc) fzw += fzw_part[(size_t)b * 4 + hc];
    const float r_wz = fminf(fzw - logZ, 0.f);
    out[b] = -(pxw - pwx + r_wz);
  }
}

extern "C" void kernel_launch(void* const* d_in, const int* in_sizes, int n_in,
                              void* d_out, int out_size, void* d_ws, size_t ws_size,
                              hipStream_t stream) {
  const float* x    = (const float*)d_in[0];
  // d_in[1] = y, unused
  const float* w    = (const float*)d_in[2];
  const float* z    = (const float*)d_in[3];
  const float* wt   = (const float*)d_in[4];
  const float* W    = (const float*)d_in[5];
  const float* bvec = (const float*)d_in[6];
  const float* cvec = (const float*)d_in[7];
  const float* W1   = (const float*)d_in[8];
  const float* b1   = (const float*)d_in[9];
  const float* W2   = (const float*)d_in[10];
  const float* b2   = (const float*)d_in[11];

  float* ws_f = (float*)d_ws;
  unsigned short* Bp    = (unsigned short*)ws_f;              // 65536 us = 32768 f
  float* zb1            = ws_f + 32768;                       // 65536 f
  float* l2part         = ws_f + 98304;                       // 262144 f
  float* pxw_part       = ws_f + 360448;                      // 1024 f
  float* fzw_part       = ws_f + 361472;                      // 512 f
  float* mpart          = ws_f + 361984;                      // 1024 f
  float* lpart          = ws_f + 363008;                      // 1024 f
  float* out = (float*)d_out;

  hipLaunchKernelGGL(Kprep3, dim3(2208), dim3(256), 0, stream,
                     x, w, z, W, cvec, W1, b1, W2, Bp, l2part, zb1, pxw_part, fzw_part);
  hipLaunchKernelGGL(Kmfma, dim3(1024), dim3(256), 0, stream,
                     wt, Bp, zb1, W2, b2, mpart, lpart);
  hipLaunchKernelGGL(Kfin, dim3(B_), dim3(128), 0, stream,
                     mpart, lpart, l2part, bvec, w, pxw_part, fzw_part, b2, out);
}